// Round 10
// baseline (198.498 us; speedup 1.0000x reference)
//
#include <hip/hip_runtime.h>

#define BLOCK  256
#define TSPLIT 32    // target chunks per batch

typedef float vfloat2 __attribute__((ext_vector_type(2)));
typedef float vfloat4 __attribute__((ext_vector_type(4)));

__device__ __forceinline__ vfloat2 vlo(vfloat4 v) { return __builtin_shufflevector(v, v, 0, 1); }
__device__ __forceinline__ vfloat2 vhi(vfloat4 v) { return __builtin_shufflevector(v, v, 2, 3); }

// order-preserving float -> uint key (works for negatives too)
__device__ __forceinline__ unsigned fkey(float f) {
    unsigned b = __float_as_uint(f);
    return b ^ ((unsigned)((int)b >> 31) | 0x80000000u);
}
__device__ __forceinline__ float funkey(unsigned k) {
    unsigned b = (k & 0x80000000u) ? (k ^ 0x80000000u) : ~k;
    return __uint_as_float(b);
}

// ---- Kernel A: repack targets to SoA (TX|TY|TZ|TW) with pad sentinels;
//      init minbuf to max-key and zero the completion counter. ----
__global__ __launch_bounds__(256) void prep_kernel(
    const float* __restrict__ tgt, float* __restrict__ soa,
    unsigned* __restrict__ minbuf, unsigned* __restrict__ counter,
    int M, int Mp, int BMp, int BN)
{
    int i = blockIdx.x * 256 + threadIdx.x;
    if (i == 0) *counter = 0u;
    if (i < BN) minbuf[i] = 0xFFFFFFFFu;
    if (i >= BMp) return;
    int b = i / Mp, m = i - b * Mp;
    float x = 0.f, y = 0.f, z = 0.f, w = 1e30f;  // pad: never wins the min
    if (m < M) {
        const float* p = tgt + ((size_t)b * M + m) * 3;
        x = p[0]; y = p[1]; z = p[2];
        w = fmaf(x, x, fmaf(y, y, z * z));
    }
    soa[i]           = x;
    soa[BMp + i]     = y;
    soa[2 * BMp + i] = z;
    soa[3 * BMp + i] = w;
}

// ---- Kernel B: one SOURCE PER LANE; block scans one target chunk.
// SoA float4 loads, FMA chain seeded from |t|^2: 2.0 VALU insts/pair.
// Finish: s^2 + chunk-min -> ordered-int atomicMin into minbuf; the LAST
// block (completion counter) reduces minbuf and writes the scalar loss.
__global__ __launch_bounds__(BLOCK, 8) void nn_chunk_kernel(
    const float* __restrict__ src, const float* __restrict__ soa,
    unsigned* __restrict__ minbuf, unsigned* __restrict__ counter,
    float* __restrict__ out, int N, int Mp, int BMp, int SGB, int BN,
    float scale)
{
    const int tid = threadIdx.x;
    const int c   = blockIdx.x % TSPLIT;         // target chunk  (uniform)
    const int sgg = blockIdx.x / TSPLIT;
    const int b   = sgg / SGB;                   // batch         (uniform)
    const int sgl = sgg - b * SGB;
    const int si  = sgl * BLOCK + tid;           // source within batch

    float x = 0.f, y = 0.f, z = 0.f;
    if (si < N) {
        const float* p = src + ((size_t)b * N + si) * 3;
        x = p[0]; y = p[1]; z = p[2];
    }
    const vfloat2 nsx = {-2.f * x, -2.f * x};
    const vfloat2 nsy = {-2.f * y, -2.f * y};
    const vfloat2 nsz = {-2.f * z, -2.f * z};
    float mind = 1e30f;

    const int CHT = Mp / TSPLIT;                 // targets per chunk (mult of 8)
    const int f4  = (b * Mp + c * CHT) >> 2;     // uniform float4 index
    const vfloat4* __restrict__ TX = (const vfloat4*)soa;
    const vfloat4* __restrict__ TY = (const vfloat4*)(soa + BMp);
    const vfloat4* __restrict__ TZ = (const vfloat4*)(soa + 2 * BMp);
    const vfloat4* __restrict__ TW = (const vfloat4*)(soa + 3 * BMp);

#pragma unroll 2
    for (int k = 0; k < CHT / 8; ++k) {
        vfloat4 xa = TX[f4 + 2 * k], xb = TX[f4 + 2 * k + 1];
        vfloat4 ya = TY[f4 + 2 * k], yb = TY[f4 + 2 * k + 1];
        vfloat4 za = TZ[f4 + 2 * k], zb = TZ[f4 + 2 * k + 1];
        vfloat4 wa = TW[f4 + 2 * k], wb = TW[f4 + 2 * k + 1];

        vfloat2 d;
        d = __builtin_elementwise_fma(vlo(xa), nsx, vlo(wa));
        d = __builtin_elementwise_fma(vlo(ya), nsy, d);
        d = __builtin_elementwise_fma(vlo(za), nsz, d);
        mind = fminf(mind, fminf(d.x, d.y));     // v_min3_f32

        d = __builtin_elementwise_fma(vhi(xa), nsx, vhi(wa));
        d = __builtin_elementwise_fma(vhi(ya), nsy, d);
        d = __builtin_elementwise_fma(vhi(za), nsz, d);
        mind = fminf(mind, fminf(d.x, d.y));

        d = __builtin_elementwise_fma(vlo(xb), nsx, vlo(wb));
        d = __builtin_elementwise_fma(vlo(yb), nsy, d);
        d = __builtin_elementwise_fma(vlo(zb), nsz, d);
        mind = fminf(mind, fminf(d.x, d.y));

        d = __builtin_elementwise_fma(vhi(xb), nsx, vhi(wb));
        d = __builtin_elementwise_fma(vhi(yb), nsy, d);
        d = __builtin_elementwise_fma(vhi(zb), nsz, d);
        mind = fminf(mind, fminf(d.x, d.y));
    }

    // s^2 + min_rel = min ||s - t||^2 over this chunk; ordered-int atomicMin
    if (si < N) {
        float f = fmaf(x, x, fmaf(y, y, z * z)) + mind;
        atomicMin(&minbuf[b * N + si], fkey(f));
    }

    // ---- completion counter; last block finalizes ----
    __threadfence();
    __shared__ int is_last;
    if (tid == 0) {
        unsigned done = atomicAdd(counter, 1u);
        is_last = (done == (unsigned)(gridDim.x - 1)) ? 1 : 0;
    }
    __syncthreads();
    if (is_last) {
        __threadfence();  // acquire: see all other blocks' minbuf updates
        float s = 0.f;
        for (int j = tid; j < BN; j += BLOCK) {
            unsigned k = __hip_atomic_load(&minbuf[j], __ATOMIC_RELAXED,
                                           __HIP_MEMORY_SCOPE_AGENT);
            s += funkey(k);
        }
#pragma unroll
        for (int off = 32; off > 0; off >>= 1) s += __shfl_xor(s, off, 64);
        __shared__ float wsum[BLOCK / 64];
        const int lane = tid & 63;
        const int w    = tid >> 6;
        if (lane == 0) wsum[w] = s;
        __syncthreads();
        if (tid == 0) {
            float t = 0.f;
#pragma unroll
            for (int k2 = 0; k2 < BLOCK / 64; ++k2) t += wsum[k2];
            out[0] = t * scale;
        }
    }
}

extern "C" void kernel_launch(void* const* d_in, const int* in_sizes, int n_in,
                              void* d_out, int out_size, void* d_ws, size_t ws_size,
                              hipStream_t stream) {
    const float* src = (const float*)d_in[0];  // [B, N, 3] fp32
    const float* tgt = (const float*)d_in[1];  // [B, M, 3] fp32
    float* out = (float*)d_out;                // scalar fp32

    const int B = 2;
    const int N = in_sizes[0] / (B * 3);
    const int M = in_sizes[1] / (B * 3);
    const int BN = B * N;

    // pad targets-per-batch so each chunk is a multiple of 8 targets
    const int step = TSPLIT * 8;
    const int Mp  = ((M + step - 1) / step) * step;   // 8192 stays 8192
    const int BMp = B * Mp;

    // workspace layout: counter | minbuf[BN] | soa[4*BMp]
    unsigned* counter = (unsigned*)d_ws;
    unsigned* minbuf  = counter + 64;                 // keep soa 256B-aligned
    float*    soa     = (float*)(minbuf + BN);

    int prep_n = (BMp > BN ? BMp : BN);
    prep_kernel<<<(prep_n + 255) / 256, 256, 0, stream>>>(
        tgt, soa, minbuf, counter, M, Mp, BMp, BN);

    const int SGB = (N + BLOCK - 1) / BLOCK;          // source groups / batch
    const int grid1 = B * SGB * TSPLIT;               // 2048 blocks
    nn_chunk_kernel<<<grid1, BLOCK, 0, stream>>>(
        src, soa, minbuf, counter, out, N, Mp, BMp, SGB, BN,
        1.0f / (3.0f * (float)N * (float)B));
}

// Round 11
// 72.969 us; speedup vs baseline: 2.7203x; 2.7203x over previous
//
#include <hip/hip_runtime.h>

#define BLOCK  256
#define TSPLIT 32    // target chunks (partial-min buffer depth)

typedef float vfloat2 __attribute__((ext_vector_type(2)));
typedef float vfloat4 __attribute__((ext_vector_type(4)));

__device__ __forceinline__ vfloat2 vlo(vfloat4 v) { return __builtin_shufflevector(v, v, 0, 1); }
__device__ __forceinline__ vfloat2 vhi(vfloat4 v) { return __builtin_shufflevector(v, v, 2, 3); }

// ---- Kernel A: repack targets to SoA (TX|TY|TZ|TW), pad with sentinels,
//      and zero d_out (replaces a memset node). ----
__global__ __launch_bounds__(256) void prep_kernel(
    const float* __restrict__ tgt, float* __restrict__ soa,
    float* __restrict__ out, int M, int Mp, int BMp)
{
    int i = blockIdx.x * 256 + threadIdx.x;
    if (i == 0) out[0] = 0.f;
    if (i >= BMp) return;
    int b = i / Mp, m = i - b * Mp;
    float x = 0.f, y = 0.f, z = 0.f, w = 1e30f;  // pad: never wins the min
    if (m < M) {
        const float* p = tgt + ((size_t)b * M + m) * 3;
        x = p[0]; y = p[1]; z = p[2];
        w = fmaf(x, x, fmaf(y, y, z * z));
    }
    soa[i]           = x;
    soa[BMp + i]     = y;
    soa[2 * BMp + i] = z;
    soa[3 * BMp + i] = w;
}

// ---- Kernel B (pass 1): one SOURCE PER LANE; block scans one target chunk.
// SoA float4 loads (uniform-address VECTOR loads -> L1 broadcast; do NOT add
// fences/atomics here, they flip codegen to scalar SMEM loads — R10 lesson);
// FMA chain seeded from |t|^2: 3 v_pk_fma + 1 v_min3 per 2 targets
// = 2.0 VALU insts/pair. mind is one VGPR; NO cross-lane reduction,
// NO LDS, NO barriers.
__global__ __launch_bounds__(BLOCK, 8) void nn_chunk_kernel(
    const float* __restrict__ src, const float* __restrict__ soa,
    float* __restrict__ partial, int N, int Mp, int BMp, int SGB, int BN)
{
    const int tid = threadIdx.x;
    const int c   = blockIdx.x % TSPLIT;         // target chunk  (uniform)
    const int sgg = blockIdx.x / TSPLIT;
    const int b   = sgg / SGB;                   // batch         (uniform)
    const int sgl = sgg - b * SGB;
    const int si  = sgl * BLOCK + tid;           // source within batch

    // per-lane source, pre-scaled by -2, splatted to pk pairs
    float x = 0.f, y = 0.f, z = 0.f;
    if (si < N) {
        const float* p = src + ((size_t)b * N + si) * 3;
        x = p[0]; y = p[1]; z = p[2];
    }
    const vfloat2 nsx = {-2.f * x, -2.f * x};
    const vfloat2 nsy = {-2.f * y, -2.f * y};
    const vfloat2 nsz = {-2.f * z, -2.f * z};
    float mind = 1e30f;

    // wave-uniform target pointers (float4 views of the SoA streams)
    const int CHT = Mp / TSPLIT;                 // targets per chunk (mult of 8)
    const int f4  = (b * Mp + c * CHT) >> 2;     // uniform float4 index
    const vfloat4* __restrict__ TX = (const vfloat4*)soa;
    const vfloat4* __restrict__ TY = (const vfloat4*)(soa + BMp);
    const vfloat4* __restrict__ TZ = (const vfloat4*)(soa + 2 * BMp);
    const vfloat4* __restrict__ TW = (const vfloat4*)(soa + 3 * BMp);

#pragma unroll 2
    for (int k = 0; k < CHT / 8; ++k) {
        // 8 dwordx4 loads in flight -> 8 targets
        vfloat4 xa = TX[f4 + 2 * k], xb = TX[f4 + 2 * k + 1];
        vfloat4 ya = TY[f4 + 2 * k], yb = TY[f4 + 2 * k + 1];
        vfloat4 za = TZ[f4 + 2 * k], zb = TZ[f4 + 2 * k + 1];
        vfloat4 wa = TW[f4 + 2 * k], wb = TW[f4 + 2 * k + 1];

        vfloat2 d;
        d = __builtin_elementwise_fma(vlo(xa), nsx, vlo(wa));
        d = __builtin_elementwise_fma(vlo(ya), nsy, d);
        d = __builtin_elementwise_fma(vlo(za), nsz, d);
        mind = fminf(mind, fminf(d.x, d.y));     // v_min3_f32

        d = __builtin_elementwise_fma(vhi(xa), nsx, vhi(wa));
        d = __builtin_elementwise_fma(vhi(ya), nsy, d);
        d = __builtin_elementwise_fma(vhi(za), nsz, d);
        mind = fminf(mind, fminf(d.x, d.y));

        d = __builtin_elementwise_fma(vlo(xb), nsx, vlo(wb));
        d = __builtin_elementwise_fma(vlo(yb), nsy, d);
        d = __builtin_elementwise_fma(vlo(zb), nsz, d);
        mind = fminf(mind, fminf(d.x, d.y));

        d = __builtin_elementwise_fma(vhi(xb), nsx, vhi(wb));
        d = __builtin_elementwise_fma(vhi(yb), nsy, d);
        d = __builtin_elementwise_fma(vhi(zb), nsz, d);
        mind = fminf(mind, fminf(d.x, d.y));
    }

    if (si < N) {
        partial[(size_t)c * BN + (size_t)b * N + si] = mind;  // coalesced
    }
}

// ---- Kernel C (pass 2): per source min over chunks, +|s|^2, sum, atomic ----
__global__ __launch_bounds__(BLOCK) void reduce_kernel(
    const float* __restrict__ src, const float* __restrict__ partial,
    float* __restrict__ out, int BN, float scale)
{
    const int i = blockIdx.x * BLOCK + threadIdx.x;
    float v = 0.f;
    if (i < BN) {
        float m0 = 1e30f, m1 = 1e30f, m2 = 1e30f, m3 = 1e30f;
#pragma unroll
        for (int c = 0; c < TSPLIT; c += 4) {
            m0 = fminf(m0, partial[(size_t)(c + 0) * BN + i]);
            m1 = fminf(m1, partial[(size_t)(c + 1) * BN + i]);
            m2 = fminf(m2, partial[(size_t)(c + 2) * BN + i]);
            m3 = fminf(m3, partial[(size_t)(c + 3) * BN + i]);
        }
        float x = src[(size_t)i * 3 + 0];
        float y = src[(size_t)i * 3 + 1];
        float z = src[(size_t)i * 3 + 2];
        v = fmaf(x, x, fmaf(y, y, z * z))
          + fminf(fminf(m0, m1), fminf(m2, m3));     // = min ||s-t||^2
    }

#pragma unroll
    for (int off = 32; off > 0; off >>= 1) v += __shfl_xor(v, off, 64);

    __shared__ float wsum[BLOCK / 64];
    const int lane = threadIdx.x & 63;
    const int w    = threadIdx.x >> 6;
    if (lane == 0) wsum[w] = v;
    __syncthreads();
    if (threadIdx.x == 0) {
        float s = 0.f;
#pragma unroll
        for (int k = 0; k < BLOCK / 64; ++k) s += wsum[k];
        atomicAdd(out, s * scale);
    }
}

extern "C" void kernel_launch(void* const* d_in, const int* in_sizes, int n_in,
                              void* d_out, int out_size, void* d_ws, size_t ws_size,
                              hipStream_t stream) {
    const float* src = (const float*)d_in[0];  // [B, N, 3] fp32
    const float* tgt = (const float*)d_in[1];  // [B, M, 3] fp32
    float* out = (float*)d_out;                // scalar fp32

    const int B = 2;
    const int N = in_sizes[0] / (B * 3);
    const int M = in_sizes[1] / (B * 3);
    const int BN = B * N;

    // pad targets-per-batch so each chunk is a multiple of 8 targets
    const int step = TSPLIT * 8;
    const int Mp  = ((M + step - 1) / step) * step;   // 8192 stays 8192
    const int BMp = B * Mp;

    float* soa     = (float*)d_ws;                    // 4*BMp floats (SoA)
    float* partial = soa + 4 * (size_t)BMp;           // TSPLIT*BN floats

    prep_kernel<<<(BMp + 255) / 256, 256, 0, stream>>>(tgt, soa, out, M, Mp, BMp);

    const int SGB = (N + BLOCK - 1) / BLOCK;          // source groups / batch
    const int grid1 = B * SGB * TSPLIT;               // 2048 blocks
    nn_chunk_kernel<<<grid1, BLOCK, 0, stream>>>(src, soa, partial,
                                                 N, Mp, BMp, SGB, BN);

    reduce_kernel<<<(BN + BLOCK - 1) / BLOCK, BLOCK, 0, stream>>>(
        src, partial, out, BN, 1.0f / (3.0f * (float)N * (float)B));
}